// Round 3
// baseline (252.671 us; speedup 1.0000x reference)
//
#include <hip/hip_runtime.h>
#include <hip/hip_bf16.h>
#include <stdint.h>

typedef __bf16 bf16x8 __attribute__((ext_vector_type(8)));
typedef float  f32x4  __attribute__((ext_vector_type(4)));
using bf16 = __hip_bfloat16;

#define NNODES 8192
#define FIN    8256      // 8192 + 64
#define NCOL   192       // 128 (W1) + 64 (W2 top)
#define KTILES 129       // 8256 / 64
#define BM     128

// ---- workspace layout (bytes) ----
enum : size_t {
  WCT_OFF  = 0,            // bf16 [192][8256]   3,170,304
  CNT_OFF  = 3170304,      // int  [8192]
  OFF_OFF  = 3203072,      // int  [8193]
  CUR_OFF  = 3236096,      // int  [8192]
  DNV_OFF  = 3268864,      // f32  [8192]
  CSR_OFF  = 3301632,      // int  [262144]
  H1_OFF   = 4350208,      // f32  [8192][128]
  HX2_OFF  = 8544512,      // f32  [8192][64]
  RU_OFF   = 10641664,     // f32  [8192][128]
  H2_OFF   = 14835968,     // f32  [8192][64]
  YP_OFF   = 16933120,     // f32  [ksplit][8192][192]
  YP_SLICE = 6291456
};

__global__ void k_zero_i(int* p, int n) {
  int i = blockIdx.x * 256 + threadIdx.x;
  if (i < n) p[i] = 0;
}

__global__ void k_out_zero(float* out) {
  int i = blockIdx.x * 256 + threadIdx.x;
  if (i < NNODES * 64) out[i] = 0.f;   // diagnostic signature: absmax == stub's 3.59375
}

// LDS-tiled transpose+convert: wct[c][k] = bf16( c<128 ? W1[k][c] : (k<8192 ? W2[k][c-128] : 0) )
// grid (FIN/32 = 258, NCOL/32 = 6), 256 threads
__global__ void k_prep_wct(const float* __restrict__ W1, const float* __restrict__ W2,
                           bf16* __restrict__ wct) {
  __shared__ bf16 tile[32][33];
  const int kt = blockIdx.x * 32, ct = blockIdx.y * 32;
  const int tx = threadIdx.x & 31, ty = threadIdx.x >> 5;  // ty 0..7
#pragma unroll
  for (int r = 0; r < 4; ++r) {
    int k = kt + ty + r * 8, c = ct + tx;
    float v = 0.f;
    if (c < 128)       v = W1[(size_t)k * 128 + c];
    else if (k < 8192) v = W2[(size_t)k * 64 + (c - 128)];
    tile[ty + r * 8][tx] = __float2bfloat16(v);
  }
  __syncthreads();
#pragma unroll
  for (int r = 0; r < 4; ++r) {
    int c = ct + ty + r * 8;
    wct[(size_t)c * FIN + kt + tx] = tile[tx][ty + r * 8];
  }
}

__global__ void k_hist(const int* __restrict__ ei, int E, int* cnt) {
  int e = blockIdx.x * 256 + threadIdx.x;
  if (e < E) atomicAdd(&cnt[ei[E + e]], 1);
}

// single block, 256 threads: exclusive scan -> offsets/cursor; dinv = rsqrt(deg+1)
__global__ void k_scan(const int* __restrict__ cnt, int* __restrict__ offs,
                       int* __restrict__ cur, float* __restrict__ dinv) {
  __shared__ int part[256];
  int tid = threadIdx.x;
  int base = tid * 32;
  int s = 0;
#pragma unroll
  for (int j = 0; j < 32; j++) s += cnt[base + j];
  part[tid] = s;
  __syncthreads();
  for (int off = 1; off < 256; off <<= 1) {
    int a = (tid >= off) ? part[tid - off] : 0;
    __syncthreads();
    part[tid] += a;
    __syncthreads();
  }
  int run = (tid == 0) ? 0 : part[tid - 1];
  for (int j = 0; j < 32; j++) {
    int c = cnt[base + j];
    offs[base + j] = run;
    cur[base + j]  = run;
    dinv[base + j] = rsqrtf((float)(c + 1));
    run += c;
  }
  if (tid == 255) offs[NNODES] = run;
}

__global__ void k_fill(const int* __restrict__ ei, int E, int* cur, int* __restrict__ csr) {
  int e = blockIdx.x * 256 + threadIdx.x;
  if (e < E) {
    int d = ei[E + e];
    int p = atomicAdd(&cur[d], 1);
    csr[p] = ei[e];
  }
}

__device__ __forceinline__ uint4 pack8(float4 a, float4 b) {
  union { bf16 h[8]; uint4 v; } u;
  u.h[0] = __float2bfloat16(a.x); u.h[1] = __float2bfloat16(a.y);
  u.h[2] = __float2bfloat16(a.z); u.h[3] = __float2bfloat16(a.w);
  u.h[4] = __float2bfloat16(b.x); u.h[5] = __float2bfloat16(b.y);
  u.h[6] = __float2bfloat16(b.z); u.h[7] = __float2bfloat16(b.w);
  return u.v;
}

// C = [x | hidden] @ [W1 | W2top] : M=8192, N=192, K=8256; fp32 A converted to bf16
// in-register during staging. grid (64, ksplit), 512 threads (8 waves, 2x4).
// XOR slot swizzle: write and read use the SAME expression -> consistent.
__global__ __launch_bounds__(512) void k_gemm(const float* __restrict__ x,
                                              const float* __restrict__ hid,
                                              const bf16* __restrict__ wct,
                                              float* __restrict__ yp,
                                              float* __restrict__ h1d,
                                              float* __restrict__ hx2d,
                                              int tpc) {
  __shared__ uint4 smA[128][8];   // 16 KB : A rows, 8 slots of 8 bf16
  __shared__ uint4 smB[192][8];   // 24 KB : Wc columns
  const int tid = threadIdx.x;
  const int lane = tid & 63, wave = tid >> 6;
  const int wr = wave >> 2, wc = wave & 3;           // 2x4 wave grid
  const int rl = lane & 15, g = lane >> 4;
  const int m0 = blockIdx.x * BM;
  const int chunk = blockIdx.y;
  const int t_lo = chunk * tpc;
  int t_hi = t_lo + tpc;
  if (t_hi > KTILES) t_hi = KTILES;

  // A staging: 1024 units (16B LDS each <- 32B fp32 global); 2 per thread
  const float* pax[2]; const float* pah[2]; uint4* ldsA[2];
  // B staging: 1536 units (16B bf16); 3 per thread
  const bf16* pb[3]; uint4* ldsB[3];
#pragma unroll
  for (int q = 0; q < 2; ++q) {
    int u = tid + q * 512;
    int r = u >> 3, t = u & 7;
    pax[q] = x + (size_t)(m0 + r) * 8192 + t * 8;
    pah[q] = hid + (size_t)(m0 + r) * 64 + t * 8;
    ldsA[q] = &smA[r][t ^ (r & 7)];
  }
#pragma unroll
  for (int q = 0; q < 3; ++q) {
    int v = tid + q * 512;
    int c = v >> 3, t = v & 7;
    pb[q] = wct + (size_t)c * FIN + t * 8;
    ldsB[q] = &smB[c][t ^ (c & 7)];
  }

  f32x4 acc[4][3] = {};

  for (int t = t_lo; t < t_hi; ++t) {
    const int k0 = t * 64;
    float4 a0[2], a1[2];
    uint4 bv[3];
#pragma unroll
    for (int q = 0; q < 2; ++q) {
      const float* p = (k0 < 8192) ? (pax[q] + k0) : (pah[q] + (k0 - 8192));
      a0[q] = ((const float4*)p)[0];
      a1[q] = ((const float4*)p)[1];
    }
#pragma unroll
    for (int q = 0; q < 3; ++q) bv[q] = *(const uint4*)(pb[q] + k0);

    __syncthreads();   // prior iteration's fragment reads complete
#pragma unroll
    for (int q = 0; q < 2; ++q) *ldsA[q] = pack8(a0[q], a1[q]);
#pragma unroll
    for (int q = 0; q < 3; ++q) *ldsB[q] = bv[q];
    __syncthreads();

#pragma unroll
    for (int kk = 0; kk < 2; ++kk) {
      bf16x8 af[4], bfr[3];
#pragma unroll
      for (int mf = 0; mf < 4; ++mf) {
        int r = wr * 64 + mf * 16 + rl;
        af[mf] = *(const bf16x8*)&smA[r][(g ^ (rl & 7)) ^ (kk * 4)];
      }
#pragma unroll
      for (int nf = 0; nf < 3; ++nf) {
        int c = wc * 48 + nf * 16 + rl;
        bfr[nf] = *(const bf16x8*)&smB[c][(g ^ (rl & 7)) ^ (kk * 4)];
      }
#pragma unroll
      for (int mf = 0; mf < 4; ++mf)
#pragma unroll
        for (int nf = 0; nf < 3; ++nf)
          acc[mf][nf] = __builtin_amdgcn_mfma_f32_16x16x32_bf16(af[mf], bfr[nf], acc[mf][nf], 0, 0, 0);
    }
  }

  // C/D layout (HW-verified): col = lane&15, row = (lane>>4)*4 + reg
  if (h1d) {  // direct mode (ksplit==1): split-write h1 / hx2, no yp
#pragma unroll
    for (int mf = 0; mf < 4; ++mf) {
      int row = m0 + wr * 64 + mf * 16 + g * 4;
#pragma unroll
      for (int nf = 0; nf < 3; ++nf) {
        int col = wc * 48 + nf * 16 + rl;
#pragma unroll
        for (int tt = 0; tt < 4; ++tt) {
          float vv = acc[mf][nf][tt];
          if (col < 128) h1d[(size_t)(row + tt) * 128 + col] = vv;
          else           hx2d[(size_t)(row + tt) * 64 + (col - 128)] = vv;
        }
      }
    }
  } else {
    float* ypc = yp + (size_t)chunk * ((size_t)NNODES * NCOL);
#pragma unroll
    for (int mf = 0; mf < 4; ++mf) {
      int row = m0 + wr * 64 + mf * 16 + g * 4;
#pragma unroll
      for (int nf = 0; nf < 3; ++nf) {
        int col = wc * 48 + nf * 16 + rl;
#pragma unroll
        for (int tt = 0; tt < 4; ++tt)
          ypc[(size_t)(row + tt) * NCOL + col] = acc[mf][nf][tt];
      }
    }
  }
}

// sum K-split partials; split into h1 [8192][128] and hx2 [8192][64]
__global__ void k_reduce(const float* __restrict__ yp, float* __restrict__ h1,
                         float* __restrict__ hx2, int nch) {
  int idx = blockIdx.x * 256 + threadIdx.x;  // < 8192*192
  float s = 0.f;
  for (int c = 0; c < nch; c++) s += yp[(size_t)c * ((size_t)NNODES * NCOL) + idx];
  int i = idx / NCOL, c = idx - i * NCOL;
  if (c < 128) h1[(size_t)i * 128 + c] = s;
  else         hx2[(size_t)i * 64 + (c - 128)] = s;
}

// one wave per node: ru = sigmoid(selfloop + sum_edges h1[src]*dinv[src]*dinv[dst] + b1)
__global__ void k_scat1(const float* __restrict__ h1, const int* __restrict__ offs,
                        const int* __restrict__ csr, const float* __restrict__ dinv,
                        const float* __restrict__ b1, float* __restrict__ ru) {
  int node = blockIdx.x * 4 + (threadIdx.x >> 6);
  int lane = threadIdx.x & 63;
  float dd = dinv[node];
  float2 v = ((const float2*)(h1 + (size_t)node * 128))[lane];
  float ax = v.x * dd * dd, ay = v.y * dd * dd;
  int e0 = offs[node], e1 = offs[node + 1];
  for (int e = e0; e < e1; ++e) {
    int s = csr[e];
    float nrm = dinv[s] * dd;
    float2 w = ((const float2*)(h1 + (size_t)s * 128))[lane];
    ax += w.x * nrm;
    ay += w.y * nrm;
  }
  ax += b1[lane * 2];
  ay += b1[lane * 2 + 1];
  ax = 1.f / (1.f + expf(-ax));
  ay = 1.f / (1.f + expf(-ay));
  ru[(size_t)node * 128 + lane * 2]     = ax;
  ru[(size_t)node * 128 + lane * 2 + 1] = ay;
}

// h2[i] = hx2[i] + (r[i] .* hidden[i]) @ W2_bottom  (r via the flat-reshape quirk)
__global__ void k_rh(const float* __restrict__ ru, const float* __restrict__ hidden,
                     const float* __restrict__ hx2, const float* __restrict__ W2,
                     float* __restrict__ h2) {
  __shared__ float W2s[64][64];
  __shared__ float rhs[4][64];
  int tid = threadIdx.x;
#pragma unroll
  for (int t = 0; t < 16; ++t) {
    int idx = tid + 256 * t;  // 4096
    int j = idx >> 6, c = idx & 63;
    W2s[j][c] = W2[(size_t)(8192 + j) * 64 + c];
  }
  int w = tid >> 6, lane = tid & 63;
  int i = blockIdx.x * 4 + w;
  float rv = ru[(size_t)(i >> 1) * 128 + ((i & 1) << 6) + lane];
  float hv = hidden[(size_t)i * 64 + lane];
  rhs[w][lane] = rv * hv;
  __syncthreads();
  float acc = hx2[(size_t)i * 64 + lane];
#pragma unroll 8
  for (int j = 0; j < 64; ++j) acc += rhs[w][j] * W2s[j][lane];
  h2[(size_t)i * 64 + lane] = acc;
}

// one wave per node: c = tanh(gather(h2)+b2); out = u*h + (1-u)*c  (u via reshape quirk)
__global__ void k_scat2(const float* __restrict__ h2, const int* __restrict__ offs,
                        const int* __restrict__ csr, const float* __restrict__ dinv,
                        const float* __restrict__ b2, const float* __restrict__ ru,
                        const float* __restrict__ hidden, float* __restrict__ out) {
  int node = blockIdx.x * 4 + (threadIdx.x >> 6);
  int lane = threadIdx.x & 63;
  float dd = dinv[node];
  float acc = h2[(size_t)node * 64 + lane] * dd * dd;
  int e0 = offs[node], e1 = offs[node + 1];
  for (int e = e0; e < e1; ++e) {
    int s = csr[e];
    acc += h2[(size_t)s * 64 + lane] * dinv[s] * dd;
  }
  acc += b2[lane];
  float cv = tanhf(acc);
  float u = ru[(size_t)(4096 + (node >> 1)) * 128 + ((node & 1) << 6) + lane];
  float hv = hidden[(size_t)node * 64 + lane];
  out[(size_t)node * 64 + lane] = u * hv + (1.f - u) * cv;
}

extern "C" void kernel_launch(void* const* d_in, const int* in_sizes, int n_in,
                              void* d_out, int out_size, void* d_ws, size_t ws_size,
                              hipStream_t stream) {
  (void)n_in; (void)out_size;
  const float* x   = (const float*)d_in[0];
  const float* hid = (const float*)d_in[1];
  const float* W1  = (const float*)d_in[2];
  const float* b1  = (const float*)d_in[3];
  const float* W2  = (const float*)d_in[4];
  const float* b2  = (const float*)d_in[5];
  const int*   ei  = (const int*)d_in[6];
  const int E = in_sizes[6] / 2;
  float* out = (float*)d_out;

  // pick K-split by available workspace; if even minimal doesn't fit,
  // emit zeros (diagnostic signature: absmax == 3.59375, same as stub)
  int ksplit;
  if      (ws_size >= YP_OFF + 4ull * YP_SLICE) ksplit = 4;
  else if (ws_size >= YP_OFF + 2ull * YP_SLICE) ksplit = 2;
  else if (ws_size >= YP_OFF)                   ksplit = 1;   // direct mode, no yp
  else {
    k_out_zero<<<dim3(NNODES * 64 / 256), dim3(256), 0, stream>>>(out);
    return;
  }
  const int tpc = (KTILES + ksplit - 1) / ksplit;

  char* ws = (char*)d_ws;
  bf16*  wct  = (bf16*)(ws + WCT_OFF);
  int*   cnt  = (int*)(ws + CNT_OFF);
  int*   offs = (int*)(ws + OFF_OFF);
  int*   cur  = (int*)(ws + CUR_OFF);
  float* dinv = (float*)(ws + DNV_OFF);
  int*   csr  = (int*)(ws + CSR_OFF);
  float* h1   = (float*)(ws + H1_OFF);
  float* hx2  = (float*)(ws + HX2_OFF);
  float* ru   = (float*)(ws + RU_OFF);
  float* h2   = (float*)(ws + H2_OFF);
  float* yp   = (float*)(ws + YP_OFF);

  k_zero_i<<<dim3(32), dim3(256), 0, stream>>>(cnt, NNODES);
  k_prep_wct<<<dim3(FIN / 32, NCOL / 32), dim3(256), 0, stream>>>(W1, W2, wct);
  k_hist<<<dim3((E + 255) / 256), dim3(256), 0, stream>>>(ei, E, cnt);
  k_scan<<<dim3(1), dim3(256), 0, stream>>>(cnt, offs, cur, dinv);
  k_fill<<<dim3((E + 255) / 256), dim3(256), 0, stream>>>(ei, E, cur, csr);
  if (ksplit == 1) {
    k_gemm<<<dim3(NNODES / BM, 1), dim3(512), 0, stream>>>(x, hid, wct, nullptr, h1, hx2, tpc);
  } else {
    k_gemm<<<dim3(NNODES / BM, ksplit), dim3(512), 0, stream>>>(x, hid, wct, yp, nullptr, nullptr, tpc);
    k_reduce<<<dim3(NNODES * NCOL / 256), dim3(256), 0, stream>>>(yp, h1, hx2, ksplit);
  }
  k_scat1<<<dim3(NNODES / 4), dim3(256), 0, stream>>>(h1, offs, csr, dinv, b1, ru);
  k_rh<<<dim3(NNODES / 4), dim3(256), 0, stream>>>(ru, hid, hx2, W2, h2);
  k_scat2<<<dim3(NNODES / 4), dim3(256), 0, stream>>>(h2, offs, csr, dinv, b2, ru, hid, out);
}